// Round 6
// baseline (970.804 us; speedup 1.0000x reference)
//
#include <hip/hip_runtime.h>

// EdgeGate: out[e] = silu(f(e) @ W1 + b1) @ W2 + b2,
//   f(e) = [|H_u - H_v| (128), H_u*H_v (128), S_e, F_e]   (258)
//
// R6: R5 failed because blockIdx%8 is not a real XCD pin and the u-sweep
// thrashed the v-window. Empirical law R1-R5: random 256B row-read costs
// ~1.2-2KB fabric traffic; dur ~= FETCH / 3.3 TB/s. This round:
//  - Balanced canonical swap (features are symmetric in u,v): (a,b) with
//    parity swap keeps segments uniform.
//  - Sort by (a/6250, b>>3): 8 a-segments; within a segment b sweeps
//    monotonically (contiguous window).
//  - Main kernel reads HW_REG_XCC_ID (real XCD id) and pulls 16-edge work
//    units from per-segment device atomics; steals other segments when done
//    (correct under ANY dispatch->XCD mapping). Per-XCD L2 footprint:
//    a-window 1.6MB resident + b-window ~1.4MB sliding = ~3MB < 4MB.
//  - Compute core unchanged from R3/R5 (f16 MFMA 16x16x32, W1 in 64KB LDS,
//    fp32 epilogue, absmax 0.0156 proven).

typedef _Float16       half8   __attribute__((ext_vector_type(8)));
typedef _Float16       half4v  __attribute__((ext_vector_type(4)));
typedef unsigned short ushort8 __attribute__((ext_vector_type(8)));
typedef float          f32x4   __attribute__((ext_vector_type(4)));

#define NSEG    8

__device__ __forceinline__ float silu_f(float x) {
    return x / (1.0f + __expf(-x));
}

// ---------------- pre-passes ----------------

__global__ __launch_bounds__(256)
void cvt_h_kernel(const float* __restrict__ H, _Float16* __restrict__ Hh, int n4) {
    int i = blockIdx.x * blockDim.x + threadIdx.x;
    if (i < n4) {
        const float4 f = ((const float4*)H)[i];
        half4v h;
        h[0] = (_Float16)f.x; h[1] = (_Float16)f.y;
        h[2] = (_Float16)f.z; h[3] = (_Float16)f.w;
        ((half4v*)Hh)[i] = h;
    }
}

__device__ __forceinline__ void canon(int u, int v, int& a, int& b) {
    const int sw = (u ^ v) & 1;       // balanced, symmetric in (u,v)
    a = sw ? v : u;
    b = sw ? u : v;
}

__global__ __launch_bounds__(256)
void hist_kernel(const int* __restrict__ eidx, int* __restrict__ hist,
                 int E, int ASZ, int BBINS) {
    int e = blockIdx.x * blockDim.x + threadIdx.x;
    if (e < E) {
        int a, b;
        canon(eidx[e], eidx[E + e], a, b);
        atomicAdd(&hist[(a / ASZ) * BBINS + (b >> 3)], 1);
    }
}

// 2-level exclusive scan over NB bins (NB <= 65536).
__global__ __launch_bounds__(256)
void scan1_kernel(int* __restrict__ hist, int* __restrict__ bsum, int NB) {
    __shared__ int s[256];
    const int t = threadIdx.x;
    const int i = blockIdx.x * 256 + t;
    const int v = (i < NB) ? hist[i] : 0;
    s[t] = v;
    __syncthreads();
    for (int off = 1; off < 256; off <<= 1) {
        const int x = (t >= off) ? s[t - off] : 0;
        __syncthreads();
        s[t] += x;
        __syncthreads();
    }
    if (i < NB) hist[i] = s[t] - v;
    if (t == 255) bsum[blockIdx.x] = s[255];
}

__global__ __launch_bounds__(256)
void scan2_kernel(int* __restrict__ bsum, int nb1) {
    __shared__ int s[256];
    const int t = threadIdx.x;
    const int v = (t < nb1) ? bsum[t] : 0;
    s[t] = v;
    __syncthreads();
    for (int off = 1; off < 256; off <<= 1) {
        const int x = (t >= off) ? s[t - off] : 0;
        __syncthreads();
        s[t] += x;
        __syncthreads();
    }
    if (t < nb1) bsum[t] = s[t] - v;
}

__global__ __launch_bounds__(256)
void scan3_kernel(int* __restrict__ hist, const int* __restrict__ bsum, int NB) {
    const int i = blockIdx.x * 256 + threadIdx.x;
    if (i < NB) hist[i] += bsum[blockIdx.x];
}

__global__ __launch_bounds__(64)
void segb_kernel(const int* __restrict__ hist, int* __restrict__ vbs,
                 int BBINS, int E) {
    const int t = threadIdx.x;
    if (t < NSEG) vbs[t] = hist[t * BBINS];
    else if (t == NSEG) vbs[NSEG] = E;
}

__global__ __launch_bounds__(256)
void scatter_kernel(const int* __restrict__ eidx, const float* __restrict__ Se,
                    const float* __restrict__ Fe, int* __restrict__ ofs,
                    int4* __restrict__ recs, int E, int ASZ, int BBINS) {
    int e = blockIdx.x * blockDim.x + threadIdx.x;
    if (e < E) {
        int a, b;
        canon(eidx[e], eidx[E + e], a, b);
        const int key = (a / ASZ) * BBINS + (b >> 3);
        const int pos = atomicAdd(&ofs[key], 1);
        _Float16 sh = (_Float16)Se[e];
        _Float16 fh = (_Float16)Fe[e];
        unsigned pk = (unsigned)*(unsigned short*)&sh
                    | ((unsigned)*(unsigned short*)&fh << 16);
        recs[pos] = make_int4(a, b, e, (int)pk);
    }
}

// ---------------- W1 LDS staging (proven R3 layout) ----------------
// w1t[n][kp] f16, K-permuted: kp = c*32 + q*8 + j ;
// d = (c>>1)*32 + q*8 + (c&1)*4 + (j>>1); src row = (j&1)*128 + d.
// Stored as 16B blocks kb at kb ^ (n&7) (XOR swizzle).

__device__ __forceinline__ void stage_w1(const float* __restrict__ W1,
                                         _Float16* __restrict__ w1t, int tid) {
    const int n = tid & 127;
    const int g = tid >> 7;
    #pragma unroll
    for (int i = 0; i < 8; ++i) {
        const int kb = g + (i << 2);
        half8 tmp;
        #pragma unroll
        for (int j = 0; j < 8; ++j) {
            const int kp = (kb << 3) + j;
            const int c  = kp >> 5;
            const int r5 = kp & 31;
            const int qq = r5 >> 3;
            const int jj = r5 & 7;
            const int d  = ((c >> 1) << 5) + (qq << 3) + ((c & 1) << 2) + (jj >> 1);
            const int src = ((jj & 1) << 7) + d;
            tmp[j] = (_Float16)W1[src * 128 + n];
        }
        *(half8*)&w1t[n * 256 + ((kb ^ (n & 7)) << 3)] = tmp;
    }
}

// ---------------- main kernel: XCD-pinned segment consumers ----------------

__global__ __launch_bounds__(512, 4)
void edgegate_seg(const _Float16* __restrict__ Hh,
                  const int4*  __restrict__ recs,
                  const int*   __restrict__ vbs,   // [9] segment edge bounds
                  int*         __restrict__ ctr,   // [8] per-segment work counters
                  const float* __restrict__ W1,
                  const float* __restrict__ b1,
                  const float* __restrict__ W2,
                  const float* __restrict__ b2,
                  float*       __restrict__ out)
{
    __shared__ _Float16 w1t[128 * 256];   // 64 KiB
    const int tid = threadIdx.x;
    stage_w1(W1, w1t, tid);
    __syncthreads();

    int xcd;
    asm volatile("s_getreg_b32 %0, hwreg(HW_REG_XCC_ID)" : "=s"(xcd));
    xcd &= (NSEG - 1);

    const int lane = tid & 63;
    const int q    = lane >> 4;
    const int cb   = lane & 15;
    const int swz  = cb & 7;

    // own segment first, then steal (correct under any dispatch mapping)
    for (int sidx = 0; sidx < NSEG; ++sidx) {
        const int seg = (xcd + sidx) & (NSEG - 1);
        const int vs  = vbs[seg];
        const int ve  = vbs[seg + 1];
        const int ner = ve - vs;
        if (ner <= 0) continue;
        const int T16 = (ner + 15) >> 4;

        while (true) {
            int t0 = 0;
            if (lane == 0) t0 = atomicAdd(&ctr[seg], 1);
            t0 = __shfl(t0, 0);
            if (t0 >= T16) break;
            const int ebase = vs + (t0 << 4);

            const int e = min(ebase + cb, ve - 1);    // clamp; stores guarded
            const int4 r = recs[e];
            const int a = r.x, b = r.y, oe = r.z;
            const unsigned pk = (unsigned)r.w;
            const unsigned short sl = (unsigned short)(pk & 0xFFFF);
            const unsigned short fl = (unsigned short)(pk >> 16);
            const float Sf = (float)*(const _Float16*)&sl;
            const float Ff = (float)*(const _Float16*)&fl;

            const _Float16* up = Hh + (size_t)a * 128;
            const _Float16* vp = Hh + (size_t)b * 128;

            f32x4 acc[8];
            #pragma unroll
            for (int t = 0; t < 8; ++t) acc[t] = (f32x4){0.f, 0.f, 0.f, 0.f};

            #pragma unroll
            for (int c8 = 0; c8 < 4; ++c8) {
                const half8 u8 = *(const half8*)(up + (c8 << 5) + (q << 3));
                const half8 v8 = *(const half8*)(vp + (c8 << 5) + (q << 3));
                half8 d8 = u8 - v8;
                ushort8 du = *(ushort8*)&d8;
                du = du & (unsigned short)0x7FFF;          // |diff|
                const half8 da = *(half8*)&du;
                const half8 p8 = u8 * v8;

                half8 ae, ao;
                ae[0]=da[0]; ae[1]=p8[0]; ae[2]=da[1]; ae[3]=p8[1];
                ae[4]=da[2]; ae[5]=p8[2]; ae[6]=da[3]; ae[7]=p8[3];
                ao[0]=da[4]; ao[1]=p8[4]; ao[2]=da[5]; ao[3]=p8[5];
                ao[4]=da[6]; ao[5]=p8[6]; ao[6]=da[7]; ao[7]=p8[7];

                const int kb0 = (((c8 << 1) + 0) * 4 + q) ^ swz;
                const int kb1 = (((c8 << 1) + 1) * 4 + q) ^ swz;
                #pragma unroll
                for (int t = 0; t < 8; ++t) {
                    const half8 b0 = *(const half8*)&w1t[((t << 4) + cb) * 256 + (kb0 << 3)];
                    acc[t] = __builtin_amdgcn_mfma_f32_16x16x32_f16(ae, b0, acc[t], 0, 0, 0);
                }
                #pragma unroll
                for (int t = 0; t < 8; ++t) {
                    const half8 b1f = *(const half8*)&w1t[((t << 4) + cb) * 256 + (kb1 << 3)];
                    acc[t] = __builtin_amdgcn_mfma_f32_16x16x32_f16(ao, b1f, acc[t], 0, 0, 0);
                }
            }

            // epilogue: per-quad row data via shuffle from lanes cb = q*4+r
            float s_r[4], f_r[4]; int oe_r[4];
            #pragma unroll
            for (int rr = 0; rr < 4; ++rr) {
                const int src = (q << 2) + rr;
                s_r[rr]  = __shfl(Sf, src);
                f_r[rr]  = __shfl(Ff, src);
                oe_r[rr] = __shfl(oe, src);
            }

            float rs[4] = {0.f, 0.f, 0.f, 0.f};
            #pragma unroll
            for (int t = 0; t < 8; ++t) {
                const int col    = (t << 4) + cb;
                const float w256 = W1[32768 + col];
                const float w257 = W1[32896 + col];
                const float b1c  = b1[col];
                const float w2c  = W2[col];
                const f32x4 av = acc[t];
                #pragma unroll
                for (int rr = 0; rr < 4; ++rr)
                    rs[rr] += silu_f(av[rr] + s_r[rr] * w256 + f_r[rr] * w257 + b1c) * w2c;
            }

            #pragma unroll
            for (int off = 1; off < 16; off <<= 1) {
                #pragma unroll
                for (int rr = 0; rr < 4; ++rr) rs[rr] += __shfl_xor(rs[rr], off);
            }

            if (cb == 0) {
                const float b2v = b2[0];
                #pragma unroll
                for (int rr = 0; rr < 4; ++rr) {
                    const int pe = ebase + (q << 2) + rr;
                    if (pe < ve) out[oe_r[rr]] = rs[rr] + b2v;
                }
            }
        }
    }
}

// ---------------- fallback (unsorted, f16 or fp32) ----------------

template<bool F16>
__global__ __launch_bounds__(512, 4)
void edgegate_kernel(const float* __restrict__ H,
                     const _Float16* __restrict__ Hh,
                     const int*   __restrict__ eidx,
                     const float* __restrict__ Se,
                     const float* __restrict__ Fe,
                     const float* __restrict__ W1,
                     const float* __restrict__ b1,
                     const float* __restrict__ W2,
                     const float* __restrict__ b2,
                     float*       __restrict__ out,
                     int E, int ntiles)
{
    __shared__ _Float16 w1t[128 * 256];
    const int tid = threadIdx.x;
    stage_w1(W1, w1t, tid);
    __syncthreads();

    const int lane = tid & 63;
    const int wave = tid >> 6;
    const int q    = lane >> 4;
    const int cb   = lane & 15;
    const int swz  = cb & 7;

    for (int tile = blockIdx.x; tile < ntiles; tile += gridDim.x) {
        const int ebase = tile * 128 + wave * 16;
        int e = ebase + cb;
        if (e >= E) e = E - 1;
        const int u = eidx[e];
        const int v = eidx[E + e];

        f32x4 acc[8];
        #pragma unroll
        for (int t = 0; t < 8; ++t) acc[t] = (f32x4){0.f, 0.f, 0.f, 0.f};

        #pragma unroll
        for (int c8 = 0; c8 < 4; ++c8) {
            half8 ae, ao;
            if constexpr (F16) {
                const _Float16* up = Hh + (size_t)u * 128;
                const _Float16* vp = Hh + (size_t)v * 128;
                const half8 u8 = *(const half8*)(up + (c8 << 5) + (q << 3));
                const half8 v8 = *(const half8*)(vp + (c8 << 5) + (q << 3));
                half8 d8 = u8 - v8;
                ushort8 du = *(ushort8*)&d8;
                du = du & (unsigned short)0x7FFF;
                const half8 da = *(half8*)&du;
                const half8 p8 = u8 * v8;
                ae[0]=da[0]; ae[1]=p8[0]; ae[2]=da[1]; ae[3]=p8[1];
                ae[4]=da[2]; ae[5]=p8[2]; ae[6]=da[3]; ae[7]=p8[3];
                ao[0]=da[4]; ao[1]=p8[4]; ao[2]=da[5]; ao[3]=p8[5];
                ao[4]=da[6]; ao[5]=p8[6]; ao[6]=da[7]; ao[7]=p8[7];
            } else {
                const float* up = H + (size_t)u * 128;
                const float* vp = H + (size_t)v * 128;
                const float4 uu0 = *(const float4*)(up + (c8 << 5) + (q << 3));
                const float4 vv0 = *(const float4*)(vp + (c8 << 5) + (q << 3));
                const float4 uu1 = *(const float4*)(up + (c8 << 5) + (q << 3) + 4);
                const float4 vv1 = *(const float4*)(vp + (c8 << 5) + (q << 3) + 4);
                ae[0]=(_Float16)fabsf(uu0.x-vv0.x); ae[1]=(_Float16)(uu0.x*vv0.x);
                ae[2]=(_Float16)fabsf(uu0.y-vv0.y); ae[3]=(_Float16)(uu0.y*vv0.y);
                ae[4]=(_Float16)fabsf(uu0.z-vv0.z); ae[5]=(_Float16)(uu0.z*vv0.z);
                ae[6]=(_Float16)fabsf(uu0.w-vv0.w); ae[7]=(_Float16)(uu0.w*vv0.w);
                ao[0]=(_Float16)fabsf(uu1.x-vv1.x); ao[1]=(_Float16)(uu1.x*vv1.x);
                ao[2]=(_Float16)fabsf(uu1.y-vv1.y); ao[3]=(_Float16)(uu1.y*vv1.y);
                ao[4]=(_Float16)fabsf(uu1.z-vv1.z); ao[5]=(_Float16)(uu1.z*vv1.z);
                ao[6]=(_Float16)fabsf(uu1.w-vv1.w); ao[7]=(_Float16)(uu1.w*vv1.w);
            }
            const int kb0 = (((c8 << 1) + 0) * 4 + q) ^ swz;
            const int kb1 = (((c8 << 1) + 1) * 4 + q) ^ swz;
            #pragma unroll
            for (int t = 0; t < 8; ++t) {
                const half8 b0 = *(const half8*)&w1t[((t << 4) + cb) * 256 + (kb0 << 3)];
                acc[t] = __builtin_amdgcn_mfma_f32_16x16x32_f16(ae, b0, acc[t], 0, 0, 0);
            }
            #pragma unroll
            for (int t = 0; t < 8; ++t) {
                const half8 b1f = *(const half8*)&w1t[((t << 4) + cb) * 256 + (kb1 << 3)];
                acc[t] = __builtin_amdgcn_mfma_f32_16x16x32_f16(ao, b1f, acc[t], 0, 0, 0);
            }
        }

        const int e0  = ebase + (q << 2);
        const int e0c = (e0 + 3 < E) ? e0 : (E - 4);
        const float4 s4 = *(const float4*)(Se + e0c);
        const float4 f4 = *(const float4*)(Fe + e0c);

        float rs0 = 0.f, rs1 = 0.f, rs2 = 0.f, rs3 = 0.f;
        #pragma unroll
        for (int t = 0; t < 8; ++t) {
            const int col    = (t << 4) + cb;
            const float w256 = W1[32768 + col];
            const float w257 = W1[32896 + col];
            const float b1c  = b1[col];
            const float w2c  = W2[col];
            const f32x4 av = acc[t];
            rs0 += silu_f(av[0] + s4.x * w256 + f4.x * w257 + b1c) * w2c;
            rs1 += silu_f(av[1] + s4.y * w256 + f4.y * w257 + b1c) * w2c;
            rs2 += silu_f(av[2] + s4.z * w256 + f4.z * w257 + b1c) * w2c;
            rs3 += silu_f(av[3] + s4.w * w256 + f4.w * w257 + b1c) * w2c;
        }
        #pragma unroll
        for (int off = 1; off < 16; off <<= 1) {
            rs0 += __shfl_xor(rs0, off);
            rs1 += __shfl_xor(rs1, off);
            rs2 += __shfl_xor(rs2, off);
            rs3 += __shfl_xor(rs3, off);
        }
        if (cb == 0 && e0 < E) {
            const float b2v = b2[0];
            out[e0]     = rs0 + b2v;
            out[e0 + 1] = rs1 + b2v;
            out[e0 + 2] = rs2 + b2v;
            out[e0 + 3] = rs3 + b2v;
        }
    }
}

// ---------------- launch ----------------

static inline size_t align256(size_t x) { return (x + 255) & ~(size_t)255; }

extern "C" void kernel_launch(void* const* d_in, const int* in_sizes, int n_in,
                              void* d_out, int out_size, void* d_ws, size_t ws_size,
                              hipStream_t stream)
{
    const float* H    = (const float*)d_in[0];
    const int*   eidx = (const int*)  d_in[1];
    const float* Se   = (const float*)d_in[2];
    const float* Fe   = (const float*)d_in[3];
    const float* W1   = (const float*)d_in[4];
    const float* b1   = (const float*)d_in[5];
    const float* W2   = (const float*)d_in[6];
    const float* b2   = (const float*)d_in[7];
    float* out = (float*)d_out;

    const int nH     = in_sizes[0];            // 6.4M floats
    const int nNodes = nH / 128;               // 50000
    const int E      = in_sizes[2];            // 600000
    const int ntiles = (E + 127) / 128;

    const int ASZ   = (nNodes + NSEG - 1) / NSEG;   // 6250 nodes per a-segment
    const int BBINS = (nNodes + 7) >> 3;            // 6250 b-bins (8 nodes each)
    const int NB    = NSEG * BBINS;                 // 50000 bins
    const int nb1   = (NB + 255) / 256;             // <= 256 required

    const size_t hhB    = (size_t)nH * sizeof(_Float16);
    const size_t off_g  = align256(hhB);                          // hist + ctr
    const size_t off_bs = align256(off_g + (size_t)(NB + 8) * 4); // bsum
    const size_t off_vb = align256(off_bs + 256 * 4);             // vbs[9]
    const size_t off_r  = align256(off_vb + 16 * 4);              // recs
    const size_t need   = off_r + (size_t)E * sizeof(int4);

    if (ws_size >= need && nb1 <= 256) {
        _Float16* Hh   = (_Float16*)((char*)d_ws);
        int*      hist = (int*)     ((char*)d_ws + off_g);
        int*      ctr  = hist + NB;                       // 8 counters
        int*      bsum = (int*)     ((char*)d_ws + off_bs);
        int*      vbs  = (int*)     ((char*)d_ws + off_vb);
        int4*     recs = (int4*)    ((char*)d_ws + off_r);

        const int n4 = nH / 4;
        hipLaunchKernelGGL(cvt_h_kernel, dim3((n4 + 255) / 256), dim3(256), 0, stream,
                           H, Hh, n4);
        hipMemsetAsync(hist, 0, (size_t)(NB + 8) * 4, stream);
        hipLaunchKernelGGL(hist_kernel, dim3((E + 255) / 256), dim3(256), 0, stream,
                           eidx, hist, E, ASZ, BBINS);
        hipLaunchKernelGGL(scan1_kernel, dim3(nb1), dim3(256), 0, stream,
                           hist, bsum, NB);
        hipLaunchKernelGGL(scan2_kernel, dim3(1), dim3(256), 0, stream, bsum, nb1);
        hipLaunchKernelGGL(scan3_kernel, dim3(nb1), dim3(256), 0, stream,
                           hist, bsum, NB);
        hipLaunchKernelGGL(segb_kernel, dim3(1), dim3(64), 0, stream,
                           hist, vbs, BBINS, E);
        hipLaunchKernelGGL(scatter_kernel, dim3((E + 255) / 256), dim3(256), 0, stream,
                           eidx, Se, Fe, hist, recs, E, ASZ, BBINS);

        hipLaunchKernelGGL(edgegate_seg, dim3(512), dim3(512), 0, stream,
                           Hh, recs, vbs, ctr, W1, b1, W2, b2, out);
    } else if (ws_size >= hhB) {
        _Float16* Hh = (_Float16*)d_ws;
        const int n4 = nH / 4;
        const int grid = (512 < ntiles) ? 512 : ntiles;
        hipLaunchKernelGGL(cvt_h_kernel, dim3((n4 + 255) / 256), dim3(256), 0, stream,
                           H, Hh, n4);
        hipLaunchKernelGGL((edgegate_kernel<true>), dim3(grid), dim3(512), 0, stream,
                           H, Hh, eidx, Se, Fe, W1, b1, W2, b2, out, E, ntiles);
    } else {
        const int grid = (512 < ntiles) ? 512 : ntiles;
        hipLaunchKernelGGL((edgegate_kernel<false>), dim3(grid), dim3(512), 0, stream,
                           H, (const _Float16*)nullptr, eidx, Se, Fe, W1, b1, W2, b2,
                           out, E, ntiles);
    }
}

// Round 7
// 295.925 us; speedup vs baseline: 3.2806x; 3.2806x over previous
//
#include <hip/hip_runtime.h>

// EdgeGate: out[e] = silu(f(e) @ W1 + b1) @ W2 + b2,
//   f(e) = [|H_u - H_v| (128), H_u*H_v (128), S_e, F_e]   (258)
//
// R7: R6 proved the locality design (FETCH 1.26GB -> 53MB: canon swap +
// (a-seg, b-bin) sort + XCC_ID-pinned ordered queues) but per-wave 16-edge
// tickets saturated the single-address atomic service rate (~70k atomics,
// demand > ~66/us service -> queue explosion -> 811us all-stall).
// Fix: ONE ticket per BLOCK per 128-edge tile (lane0 atomic -> LDS parity
// slot -> one __syncthreads; 8 waves take fixed 16-edge slices). ~8.8k
// atomics by 512 block-contenders: far under service rate even if XCC_ID
// collapses. Concurrent window/segment stays ~64 blocks x 128 edges ~ 3MB
// < 4MB L2 so the locality win is preserved.
// Compute core unchanged (f16 MFMA 16x16x32, W1 in 64KB LDS, fp32 epilogue).

typedef _Float16       half8   __attribute__((ext_vector_type(8)));
typedef _Float16       half4v  __attribute__((ext_vector_type(4)));
typedef unsigned short ushort8 __attribute__((ext_vector_type(8)));
typedef float          f32x4   __attribute__((ext_vector_type(4)));

#define NSEG    8

__device__ __forceinline__ float silu_f(float x) {
    return x / (1.0f + __expf(-x));
}

// ---------------- pre-passes ----------------

__global__ __launch_bounds__(256)
void cvt_h_kernel(const float* __restrict__ H, _Float16* __restrict__ Hh, int n4) {
    int i = blockIdx.x * blockDim.x + threadIdx.x;
    if (i < n4) {
        const float4 f = ((const float4*)H)[i];
        half4v h;
        h[0] = (_Float16)f.x; h[1] = (_Float16)f.y;
        h[2] = (_Float16)f.z; h[3] = (_Float16)f.w;
        ((half4v*)Hh)[i] = h;
    }
}

__device__ __forceinline__ void canon(int u, int v, int& a, int& b) {
    const int sw = (u ^ v) & 1;       // balanced, symmetric in (u,v)
    a = sw ? v : u;
    b = sw ? u : v;
}

__global__ __launch_bounds__(256)
void hist_kernel(const int* __restrict__ eidx, int* __restrict__ hist,
                 int E, int ASZ, int BBINS) {
    int e = blockIdx.x * blockDim.x + threadIdx.x;
    if (e < E) {
        int a, b;
        canon(eidx[e], eidx[E + e], a, b);
        atomicAdd(&hist[(a / ASZ) * BBINS + (b >> 3)], 1);
    }
}

// 2-level exclusive scan over NB bins (NB <= 65536).
__global__ __launch_bounds__(256)
void scan1_kernel(int* __restrict__ hist, int* __restrict__ bsum, int NB) {
    __shared__ int s[256];
    const int t = threadIdx.x;
    const int i = blockIdx.x * 256 + t;
    const int v = (i < NB) ? hist[i] : 0;
    s[t] = v;
    __syncthreads();
    for (int off = 1; off < 256; off <<= 1) {
        const int x = (t >= off) ? s[t - off] : 0;
        __syncthreads();
        s[t] += x;
        __syncthreads();
    }
    if (i < NB) hist[i] = s[t] - v;
    if (t == 255) bsum[blockIdx.x] = s[255];
}

__global__ __launch_bounds__(256)
void scan2_kernel(int* __restrict__ bsum, int nb1) {
    __shared__ int s[256];
    const int t = threadIdx.x;
    const int v = (t < nb1) ? bsum[t] : 0;
    s[t] = v;
    __syncthreads();
    for (int off = 1; off < 256; off <<= 1) {
        const int x = (t >= off) ? s[t - off] : 0;
        __syncthreads();
        s[t] += x;
        __syncthreads();
    }
    if (t < nb1) bsum[t] = s[t] - v;
}

__global__ __launch_bounds__(256)
void scan3_kernel(int* __restrict__ hist, const int* __restrict__ bsum, int NB) {
    const int i = blockIdx.x * 256 + threadIdx.x;
    if (i < NB) hist[i] += bsum[blockIdx.x];
}

__global__ __launch_bounds__(64)
void segb_kernel(const int* __restrict__ hist, int* __restrict__ vbs,
                 int BBINS, int E) {
    const int t = threadIdx.x;
    if (t < NSEG) vbs[t] = hist[t * BBINS];
    else if (t == NSEG) vbs[NSEG] = E;
}

__global__ __launch_bounds__(256)
void scatter_kernel(const int* __restrict__ eidx, const float* __restrict__ Se,
                    const float* __restrict__ Fe, int* __restrict__ ofs,
                    int4* __restrict__ recs, int E, int ASZ, int BBINS) {
    int e = blockIdx.x * blockDim.x + threadIdx.x;
    if (e < E) {
        int a, b;
        canon(eidx[e], eidx[E + e], a, b);
        const int key = (a / ASZ) * BBINS + (b >> 3);
        const int pos = atomicAdd(&ofs[key], 1);
        _Float16 sh = (_Float16)Se[e];
        _Float16 fh = (_Float16)Fe[e];
        unsigned pk = (unsigned)*(unsigned short*)&sh
                    | ((unsigned)*(unsigned short*)&fh << 16);
        recs[pos] = make_int4(a, b, e, (int)pk);
    }
}

// ---------------- W1 LDS staging (proven R3 layout) ----------------
// w1t[n][kp] f16, K-permuted: kp = c*32 + q*8 + j ;
// d = (c>>1)*32 + q*8 + (c&1)*4 + (j>>1); src row = (j&1)*128 + d.
// Stored as 16B blocks kb at kb ^ (n&7) (XOR swizzle).

__device__ __forceinline__ void stage_w1(const float* __restrict__ W1,
                                         _Float16* __restrict__ w1t, int tid) {
    const int n = tid & 127;
    const int g = tid >> 7;
    #pragma unroll
    for (int i = 0; i < 8; ++i) {
        const int kb = g + (i << 2);
        half8 tmp;
        #pragma unroll
        for (int j = 0; j < 8; ++j) {
            const int kp = (kb << 3) + j;
            const int c  = kp >> 5;
            const int r5 = kp & 31;
            const int qq = r5 >> 3;
            const int jj = r5 & 7;
            const int d  = ((c >> 1) << 5) + (qq << 3) + ((c & 1) << 2) + (jj >> 1);
            const int src = ((jj & 1) << 7) + d;
            tmp[j] = (_Float16)W1[src * 128 + n];
        }
        *(half8*)&w1t[n * 256 + ((kb ^ (n & 7)) << 3)] = tmp;
    }
}

// ---------------- main kernel: XCD-pinned block-ticket consumers ----------------

__global__ __launch_bounds__(512, 4)
void edgegate_seg(const _Float16* __restrict__ Hh,
                  const int4*  __restrict__ recs,
                  const int*   __restrict__ vbs,   // [9] segment edge bounds
                  int*         __restrict__ ctr,   // [8] per-segment tile counters
                  const float* __restrict__ W1,
                  const float* __restrict__ b1,
                  const float* __restrict__ W2,
                  const float* __restrict__ b2,
                  float*       __restrict__ out)
{
    __shared__ _Float16 w1t[128 * 256];   // 64 KiB
    __shared__ int tkt[2];                // parity ticket slots
    const int tid = threadIdx.x;
    stage_w1(W1, w1t, tid);

    int xcd;
    asm volatile("s_getreg_b32 %0, hwreg(HW_REG_XCC_ID)" : "=s"(xcd));
    xcd &= (NSEG - 1);

    __syncthreads();   // w1t ready

    const int lane = tid & 63;
    const int wave = tid >> 6;
    const int q    = lane >> 4;
    const int cb   = lane & 15;
    const int swz  = cb & 7;

    int p = 0;
    // own segment first, then steal (correct under any dispatch mapping)
    for (int sidx = 0; sidx < NSEG; ++sidx) {
        const int seg = (xcd + sidx) & (NSEG - 1);
        const int vs  = vbs[seg];
        const int ve  = vbs[seg + 1];
        const int ner = ve - vs;
        if (ner <= 0) continue;
        const int Tt = (ner + 127) >> 7;    // 128-edge tiles

        while (true) {
            if (tid == 0) tkt[p] = atomicAdd(&ctr[seg], 1);
            __syncthreads();
            const int t0 = tkt[p];
            p ^= 1;
            if (t0 >= Tt) break;

            const int ebase = vs + (t0 << 7) + (wave << 4);
            const int e = min(ebase + cb, ve - 1);    // clamp; stores guarded
            const int4 r = recs[e];
            const int a = r.x, b = r.y, oe = r.z;
            const unsigned pk = (unsigned)r.w;
            const unsigned short sl = (unsigned short)(pk & 0xFFFF);
            const unsigned short fl = (unsigned short)(pk >> 16);
            const float Sf = (float)*(const _Float16*)&sl;
            const float Ff = (float)*(const _Float16*)&fl;

            const _Float16* up = Hh + (size_t)a * 128;
            const _Float16* vp = Hh + (size_t)b * 128;

            f32x4 acc[8];
            #pragma unroll
            for (int t = 0; t < 8; ++t) acc[t] = (f32x4){0.f, 0.f, 0.f, 0.f};

            #pragma unroll
            for (int c8 = 0; c8 < 4; ++c8) {
                const half8 u8 = *(const half8*)(up + (c8 << 5) + (q << 3));
                const half8 v8 = *(const half8*)(vp + (c8 << 5) + (q << 3));
                half8 d8 = u8 - v8;
                ushort8 du = *(ushort8*)&d8;
                du = du & (unsigned short)0x7FFF;          // |diff|
                const half8 da = *(half8*)&du;
                const half8 p8 = u8 * v8;

                half8 ae, ao;
                ae[0]=da[0]; ae[1]=p8[0]; ae[2]=da[1]; ae[3]=p8[1];
                ae[4]=da[2]; ae[5]=p8[2]; ae[6]=da[3]; ae[7]=p8[3];
                ao[0]=da[4]; ao[1]=p8[4]; ao[2]=da[5]; ao[3]=p8[5];
                ao[4]=da[6]; ao[5]=p8[6]; ao[6]=da[7]; ao[7]=p8[7];

                const int kb0 = (((c8 << 1) + 0) * 4 + q) ^ swz;
                const int kb1 = (((c8 << 1) + 1) * 4 + q) ^ swz;
                #pragma unroll
                for (int t = 0; t < 8; ++t) {
                    const half8 b0 = *(const half8*)&w1t[((t << 4) + cb) * 256 + (kb0 << 3)];
                    acc[t] = __builtin_amdgcn_mfma_f32_16x16x32_f16(ae, b0, acc[t], 0, 0, 0);
                }
                #pragma unroll
                for (int t = 0; t < 8; ++t) {
                    const half8 b1f = *(const half8*)&w1t[((t << 4) + cb) * 256 + (kb1 << 3)];
                    acc[t] = __builtin_amdgcn_mfma_f32_16x16x32_f16(ao, b1f, acc[t], 0, 0, 0);
                }
            }

            // epilogue: per-quad row data via shuffle from lanes cb = q*4+r
            float s_r[4], f_r[4]; int oe_r[4];
            #pragma unroll
            for (int rr = 0; rr < 4; ++rr) {
                const int src = (q << 2) + rr;
                s_r[rr]  = __shfl(Sf, src);
                f_r[rr]  = __shfl(Ff, src);
                oe_r[rr] = __shfl(oe, src);
            }

            float rs[4] = {0.f, 0.f, 0.f, 0.f};
            #pragma unroll
            for (int t = 0; t < 8; ++t) {
                const int col    = (t << 4) + cb;
                const float w256 = W1[32768 + col];
                const float w257 = W1[32896 + col];
                const float b1c  = b1[col];
                const float w2c  = W2[col];
                const f32x4 av = acc[t];
                #pragma unroll
                for (int rr = 0; rr < 4; ++rr)
                    rs[rr] += silu_f(av[rr] + s_r[rr] * w256 + f_r[rr] * w257 + b1c) * w2c;
            }

            #pragma unroll
            for (int off = 1; off < 16; off <<= 1) {
                #pragma unroll
                for (int rr = 0; rr < 4; ++rr) rs[rr] += __shfl_xor(rs[rr], off);
            }

            if (cb == 0) {
                const float b2v = b2[0];
                #pragma unroll
                for (int rr = 0; rr < 4; ++rr) {
                    const int pe = ebase + (q << 2) + rr;
                    if (pe < ve) out[oe_r[rr]] = rs[rr] + b2v;
                }
            }
        }
    }
}

// ---------------- fallback (unsorted, f16 or fp32) ----------------

template<bool F16>
__global__ __launch_bounds__(512, 4)
void edgegate_kernel(const float* __restrict__ H,
                     const _Float16* __restrict__ Hh,
                     const int*   __restrict__ eidx,
                     const float* __restrict__ Se,
                     const float* __restrict__ Fe,
                     const float* __restrict__ W1,
                     const float* __restrict__ b1,
                     const float* __restrict__ W2,
                     const float* __restrict__ b2,
                     float*       __restrict__ out,
                     int E, int ntiles)
{
    __shared__ _Float16 w1t[128 * 256];
    const int tid = threadIdx.x;
    stage_w1(W1, w1t, tid);
    __syncthreads();

    const int lane = tid & 63;
    const int wave = tid >> 6;
    const int q    = lane >> 4;
    const int cb   = lane & 15;
    const int swz  = cb & 7;

    for (int tile = blockIdx.x; tile < ntiles; tile += gridDim.x) {
        const int ebase = tile * 128 + wave * 16;
        int e = ebase + cb;
        if (e >= E) e = E - 1;
        const int u = eidx[e];
        const int v = eidx[E + e];

        f32x4 acc[8];
        #pragma unroll
        for (int t = 0; t < 8; ++t) acc[t] = (f32x4){0.f, 0.f, 0.f, 0.f};

        #pragma unroll
        for (int c8 = 0; c8 < 4; ++c8) {
            half8 ae, ao;
            if constexpr (F16) {
                const _Float16* up = Hh + (size_t)u * 128;
                const _Float16* vp = Hh + (size_t)v * 128;
                const half8 u8 = *(const half8*)(up + (c8 << 5) + (q << 3));
                const half8 v8 = *(const half8*)(vp + (c8 << 5) + (q << 3));
                half8 d8 = u8 - v8;
                ushort8 du = *(ushort8*)&d8;
                du = du & (unsigned short)0x7FFF;
                const half8 da = *(half8*)&du;
                const half8 p8 = u8 * v8;
                ae[0]=da[0]; ae[1]=p8[0]; ae[2]=da[1]; ae[3]=p8[1];
                ae[4]=da[2]; ae[5]=p8[2]; ae[6]=da[3]; ae[7]=p8[3];
                ao[0]=da[4]; ao[1]=p8[4]; ao[2]=da[5]; ao[3]=p8[5];
                ao[4]=da[6]; ao[5]=p8[6]; ao[6]=da[7]; ao[7]=p8[7];
            } else {
                const float* up = H + (size_t)u * 128;
                const float* vp = H + (size_t)v * 128;
                const float4 uu0 = *(const float4*)(up + (c8 << 5) + (q << 3));
                const float4 vv0 = *(const float4*)(vp + (c8 << 5) + (q << 3));
                const float4 uu1 = *(const float4*)(up + (c8 << 5) + (q << 3) + 4);
                const float4 vv1 = *(const float4*)(vp + (c8 << 5) + (q << 3) + 4);
                ae[0]=(_Float16)fabsf(uu0.x-vv0.x); ae[1]=(_Float16)(uu0.x*vv0.x);
                ae[2]=(_Float16)fabsf(uu0.y-vv0.y); ae[3]=(_Float16)(uu0.y*vv0.y);
                ae[4]=(_Float16)fabsf(uu0.z-vv0.z); ae[5]=(_Float16)(uu0.z*vv0.z);
                ae[6]=(_Float16)fabsf(uu0.w-vv0.w); ae[7]=(_Float16)(uu0.w*vv0.w);
                ao[0]=(_Float16)fabsf(uu1.x-vv1.x); ao[1]=(_Float16)(uu1.x*vv1.x);
                ao[2]=(_Float16)fabsf(uu1.y-vv1.y); ao[3]=(_Float16)(uu1.y*vv1.y);
                ao[4]=(_Float16)fabsf(uu1.z-vv1.z); ao[5]=(_Float16)(uu1.z*vv1.z);
                ao[6]=(_Float16)fabsf(uu1.w-vv1.w); ao[7]=(_Float16)(uu1.w*vv1.w);
            }
            const int kb0 = (((c8 << 1) + 0) * 4 + q) ^ swz;
            const int kb1 = (((c8 << 1) + 1) * 4 + q) ^ swz;
            #pragma unroll
            for (int t = 0; t < 8; ++t) {
                const half8 b0 = *(const half8*)&w1t[((t << 4) + cb) * 256 + (kb0 << 3)];
                acc[t] = __builtin_amdgcn_mfma_f32_16x16x32_f16(ae, b0, acc[t], 0, 0, 0);
            }
            #pragma unroll
            for (int t = 0; t < 8; ++t) {
                const half8 b1f = *(const half8*)&w1t[((t << 4) + cb) * 256 + (kb1 << 3)];
                acc[t] = __builtin_amdgcn_mfma_f32_16x16x32_f16(ao, b1f, acc[t], 0, 0, 0);
            }
        }

        const int e0  = ebase + (q << 2);
        const int e0c = (e0 + 3 < E) ? e0 : (E - 4);
        const float4 s4 = *(const float4*)(Se + e0c);
        const float4 f4 = *(const float4*)(Fe + e0c);

        float rs0 = 0.f, rs1 = 0.f, rs2 = 0.f, rs3 = 0.f;
        #pragma unroll
        for (int t = 0; t < 8; ++t) {
            const int col    = (t << 4) + cb;
            const float w256 = W1[32768 + col];
            const float w257 = W1[32896 + col];
            const float b1c  = b1[col];
            const float w2c  = W2[col];
            const f32x4 av = acc[t];
            rs0 += silu_f(av[0] + s4.x * w256 + f4.x * w257 + b1c) * w2c;
            rs1 += silu_f(av[1] + s4.y * w256 + f4.y * w257 + b1c) * w2c;
            rs2 += silu_f(av[2] + s4.z * w256 + f4.z * w257 + b1c) * w2c;
            rs3 += silu_f(av[3] + s4.w * w256 + f4.w * w257 + b1c) * w2c;
        }
        #pragma unroll
        for (int off = 1; off < 16; off <<= 1) {
            rs0 += __shfl_xor(rs0, off);
            rs1 += __shfl_xor(rs1, off);
            rs2 += __shfl_xor(rs2, off);
            rs3 += __shfl_xor(rs3, off);
        }
        if (cb == 0 && e0 < E) {
            const float b2v = b2[0];
            out[e0]     = rs0 + b2v;
            out[e0 + 1] = rs1 + b2v;
            out[e0 + 2] = rs2 + b2v;
            out[e0 + 3] = rs3 + b2v;
        }
    }
}

// ---------------- launch ----------------

static inline size_t align256(size_t x) { return (x + 255) & ~(size_t)255; }

extern "C" void kernel_launch(void* const* d_in, const int* in_sizes, int n_in,
                              void* d_out, int out_size, void* d_ws, size_t ws_size,
                              hipStream_t stream)
{
    const float* H    = (const float*)d_in[0];
    const int*   eidx = (const int*)  d_in[1];
    const float* Se   = (const float*)d_in[2];
    const float* Fe   = (const float*)d_in[3];
    const float* W1   = (const float*)d_in[4];
    const float* b1   = (const float*)d_in[5];
    const float* W2   = (const float*)d_in[6];
    const float* b2   = (const float*)d_in[7];
    float* out = (float*)d_out;

    const int nH     = in_sizes[0];            // 6.4M floats
    const int nNodes = nH / 128;               // 50000
    const int E      = in_sizes[2];            // 600000
    const int ntiles = (E + 127) / 128;

    const int ASZ   = (nNodes + NSEG - 1) / NSEG;   // 6250 nodes per a-segment
    const int BBINS = (nNodes + 7) >> 3;            // 6250 b-bins (8 nodes each)
    const int NB    = NSEG * BBINS;                 // 50000 bins
    const int nb1   = (NB + 255) / 256;             // <= 256 required

    const size_t hhB    = (size_t)nH * sizeof(_Float16);
    const size_t off_g  = align256(hhB);                          // hist + ctr
    const size_t off_bs = align256(off_g + (size_t)(NB + 8) * 4); // bsum
    const size_t off_vb = align256(off_bs + 256 * 4);             // vbs[9]
    const size_t off_r  = align256(off_vb + 16 * 4);              // recs
    const size_t need   = off_r + (size_t)E * sizeof(int4);

    if (ws_size >= need && nb1 <= 256) {
        _Float16* Hh   = (_Float16*)((char*)d_ws);
        int*      hist = (int*)     ((char*)d_ws + off_g);
        int*      ctr  = hist + NB;                       // 8 counters
        int*      bsum = (int*)     ((char*)d_ws + off_bs);
        int*      vbs  = (int*)     ((char*)d_ws + off_vb);
        int4*     recs = (int4*)    ((char*)d_ws + off_r);

        const int n4 = nH / 4;
        hipLaunchKernelGGL(cvt_h_kernel, dim3((n4 + 255) / 256), dim3(256), 0, stream,
                           H, Hh, n4);
        hipMemsetAsync(hist, 0, (size_t)(NB + 8) * 4, stream);
        hipLaunchKernelGGL(hist_kernel, dim3((E + 255) / 256), dim3(256), 0, stream,
                           eidx, hist, E, ASZ, BBINS);
        hipLaunchKernelGGL(scan1_kernel, dim3(nb1), dim3(256), 0, stream,
                           hist, bsum, NB);
        hipLaunchKernelGGL(scan2_kernel, dim3(1), dim3(256), 0, stream, bsum, nb1);
        hipLaunchKernelGGL(scan3_kernel, dim3(nb1), dim3(256), 0, stream,
                           hist, bsum, NB);
        hipLaunchKernelGGL(segb_kernel, dim3(1), dim3(64), 0, stream,
                           hist, vbs, BBINS, E);
        hipLaunchKernelGGL(scatter_kernel, dim3((E + 255) / 256), dim3(256), 0, stream,
                           eidx, Se, Fe, hist, recs, E, ASZ, BBINS);

        hipLaunchKernelGGL(edgegate_seg, dim3(512), dim3(512), 0, stream,
                           Hh, recs, vbs, ctr, W1, b1, W2, b2, out);
    } else if (ws_size >= hhB) {
        _Float16* Hh = (_Float16*)d_ws;
        const int n4 = nH / 4;
        const int grid = (512 < ntiles) ? 512 : ntiles;
        hipLaunchKernelGGL(cvt_h_kernel, dim3((n4 + 255) / 256), dim3(256), 0, stream,
                           H, Hh, n4);
        hipLaunchKernelGGL((edgegate_kernel<true>), dim3(grid), dim3(512), 0, stream,
                           H, Hh, eidx, Se, Fe, W1, b1, W2, b2, out, E, ntiles);
    } else {
        const int grid = (512 < ntiles) ? 512 : ntiles;
        hipLaunchKernelGGL((edgegate_kernel<false>), dim3(grid), dim3(512), 0, stream,
                           H, (const _Float16*)nullptr, eidx, Se, Fe, W1, b1, W2, b2,
                           out, E, ntiles);
    }
}